// Round 1
// baseline (36264.240 us; speedup 1.0000x reference)
//
#include <hip/hip_runtime.h>
#include <stdint.h>
#include <math.h>

// LSTM: B=256, T=1024, I=128, H=256, O=1.
// Persistent cooperative kernel: 128 WGs x 512 threads.
//   group = 8 WGs (cb=0..7), each owns 32 h-components (all 4 gates = 128 gate rows)
//   16 batch-groups (bb=0..15) x 16 batches each.
// Weights live in VGPRs as MFMA A-fragments, split hi/lo bf16 for ~fp32 precision.
// One device-scope barrier (monotonic counter) per timestep per group.

typedef __attribute__((ext_vector_type(8))) __bf16 bf16x8;
typedef __attribute__((ext_vector_type(4))) float f32x4;
typedef __attribute__((ext_vector_type(8))) unsigned short ushort8;
typedef unsigned short u16;
typedef unsigned int u32;

#define NCB 8     // WGs per batch-group
#define BK  16    // batches per group
#define JP  32    // h-components per WG
#define TT  1024
#define HD  256
#define ID  128

__device__ __forceinline__ u16 f2bf(float f) {          // fp32 -> bf16 RNE
  u32 u = __float_as_uint(f);
  u += 0x7FFFu + ((u >> 16) & 1u);
  return (u16)(u >> 16);
}
__device__ __forceinline__ float bf2f(u16 h) { return __uint_as_float((u32)h << 16); }

__device__ __forceinline__ f32x4 mfma(bf16x8 a, bf16x8 b, f32x4 c) {
  return __builtin_amdgcn_mfma_f32_16x16x32_bf16(a, b, c, 0, 0, 0);
}

__global__ __launch_bounds__(512, 2) void lstm_pk(
    const float* __restrict__ x, const float* __restrict__ Wih,
    const float* __restrict__ Whh, const float* __restrict__ bih,
    const float* __restrict__ bhh, const float* __restrict__ Wfc,
    const float* __restrict__ bfc, float* __restrict__ out,
    u16* __restrict__ hgHI, u16* __restrict__ hgLO, u32* __restrict__ cnt)
{
  // LDS: pads chosen so b128 frag reads land 2-way bank aliased (free).
  __shared__ u16 hHI[16][264], hLO[16][264];        // h stage: [batch][k], stride 528B
  __shared__ u16 xHI[2][16][136], xLO[2][16][136];  // x stage (dbuf): stride 272B
  __shared__ float gex[128 * 16];                   // gate exchange [row][batch]
  __shared__ float cst[512];                        // c state, one cell per thread
  __shared__ float bias[128];
  __shared__ float red[16];

  const int tid  = threadIdx.x;
  const int bb   = blockIdx.x & 15, cb = blockIdx.x >> 4;
  const int b0   = bb * BK;
  const int lane = tid & 63, wave = tid >> 6;
  const int koff = (lane >> 4) * 8;                 // A/B frag k-offset
  const int arow = wave * 16 + (lane & 15);         // local gate-row for A frag
  const int grow = (arow >> 5) * HD + cb * JP + (arow & 31); // global W row (gate-major i,f,g,o)
  const int brow = lane & 15;                       // B frag column = batch

  // ---- weights -> VGPR fragments, hi/lo split (one-time) ----
  bf16x8 ahh_h[8], ahh_l[8], aih_h[4], aih_l[4];
#pragma unroll
  for (int kk = 0; kk < 8; ++kk) {
    const float* s = Whh + (size_t)grow * HD + kk * 32 + koff;
    float4 w0 = *(const float4*)(s), w1 = *(const float4*)(s + 4);
    float w[8] = {w0.x, w0.y, w0.z, w0.w, w1.x, w1.y, w1.z, w1.w};
    union { bf16x8 v; u16 u[8]; } th, tl;
#pragma unroll
    for (int e = 0; e < 8; ++e) {
      u16 hi = f2bf(w[e]); th.u[e] = hi; tl.u[e] = f2bf(w[e] - bf2f(hi));
    }
    ahh_h[kk] = th.v; ahh_l[kk] = tl.v;
  }
#pragma unroll
  for (int kk = 0; kk < 4; ++kk) {
    const float* s = Wih + (size_t)grow * ID + kk * 32 + koff;
    float4 w0 = *(const float4*)(s), w1 = *(const float4*)(s + 4);
    float w[8] = {w0.x, w0.y, w0.z, w0.w, w1.x, w1.y, w1.z, w1.w};
    union { bf16x8 v; u16 u[8]; } th, tl;
#pragma unroll
    for (int e = 0; e < 8; ++e) {
      u16 hi = f2bf(w[e]); th.u[e] = hi; tl.u[e] = f2bf(w[e] - bf2f(hi));
    }
    aih_h[kk] = th.v; aih_l[kk] = tl.v;
  }
  if (tid < 128) {
    int r = (tid >> 5) * HD + cb * JP + (tid & 31);
    bias[tid] = bih[r] + bhh[r];
  }
  cst[tid] = 0.f;

  auto stageX = [&](int t, int buf) {   // 16 batches x 128 elems, convert to hi/lo bf16
    int bi = tid >> 5, e4 = (tid & 31) * 4;
    const float4 v = *(const float4*)(x + ((size_t)(b0 + bi) * TT + t) * ID + e4);
    float vf[4] = {v.x, v.y, v.z, v.w};
    u32 hw[2], lw[2];
#pragma unroll
    for (int q = 0; q < 2; ++q) {
      u16 h0 = f2bf(vf[2 * q]),     h1 = f2bf(vf[2 * q + 1]);
      u16 l0 = f2bf(vf[2 * q] - bf2f(h0)), l1 = f2bf(vf[2 * q + 1] - bf2f(h1));
      hw[q] = (u32)h0 | ((u32)h1 << 16);
      lw[q] = (u32)l0 | ((u32)l1 << 16);
    }
    *(u32*)&xHI[buf][bi][e4]     = hw[0];
    *(u32*)&xHI[buf][bi][e4 + 2] = hw[1];
    *(u32*)&xLO[buf][bi][e4]     = lw[0];
    *(u32*)&xLO[buf][bi][e4 + 2] = lw[1];
  };

  stageX(0, 0);
  __syncthreads();

  float h_last = 0.f;

  for (int t = 0; t < TT; ++t) {
    const int p = t & 1, pn = p ^ 1;
    f32x4 a0 = {0, 0, 0, 0}, a1 = {0, 0, 0, 0}, a2 = {0, 0, 0, 0};

    // x-projection first: overlaps the spin-wait below (no h dependency)
#pragma unroll
    for (int kk = 0; kk < 4; ++kk) {
      bf16x8 bh = *(const bf16x8*)&xHI[p][brow][kk * 32 + koff];
      bf16x8 bl = *(const bf16x8*)&xLO[p][brow][kk * 32 + koff];
      a0 = mfma(aih_h[kk], bh, a0);
      a1 = mfma(aih_h[kk], bl, a1);
      a2 = mfma(aih_l[kk], bh, a2);
    }

    // wait until all 8 group members published h(t)  (t=0: buffer was memset to 0)
    if (t > 0 && tid == 0) {
      while (__hip_atomic_load(cnt + bb, __ATOMIC_RELAXED, __HIP_MEMORY_SCOPE_AGENT)
             < (u32)(NCB * t)) __builtin_amdgcn_s_sleep(1);
      __threadfence();   // acquire: invalidate stale L1/L2 before h reads
    }
    __syncthreads();

    { // stage h(t): 16 batches x 256 comps, hi+lo
      int flat = tid * 8, bi = flat >> 8, k = flat & 255;
      size_t go = ((size_t)p << 16) | ((size_t)(b0 + bi) << 8) | (size_t)k;
      *(ushort8*)&hHI[bi][k] = *(const ushort8*)(hgHI + go);
      *(ushort8*)&hLO[bi][k] = *(const ushort8*)(hgLO + go);
    }
    __syncthreads();

#pragma unroll
    for (int kk = 0; kk < 8; ++kk) {
      bf16x8 bh = *(const bf16x8*)&hHI[brow][kk * 32 + koff];
      bf16x8 bl = *(const bf16x8*)&hLO[brow][kk * 32 + koff];
      a0 = mfma(ahh_h[kk], bh, a0);
      a1 = mfma(ahh_h[kk], bl, a1);
      a2 = mfma(ahh_l[kk], bh, a2);
    }

    if (t + 1 < TT) stageX(t + 1, pn);   // prefetch next x tile into other LDS buf

    // D frag: row=(lane>>4)*4+r, col=lane&15  [m89-verified layout]
#pragma unroll
    for (int r = 0; r < 4; ++r)
      gex[(wave * 16 + (lane >> 4) * 4 + r) * 16 + (lane & 15)] = a0[r] + a1[r] + a2[r];
    __syncthreads();

    { // elementwise: one (comp j, batch b) cell per thread
      int j = tid >> 4, b = tid & 15;
      float gi  = gex[(j      ) * 16 + b] + bias[j];
      float gf  = gex[(32 + j ) * 16 + b] + bias[32 + j];
      float gg  = gex[(64 + j ) * 16 + b] + bias[64 + j];
      float go_ = gex[(96 + j ) * 16 + b] + bias[96 + j];
      float is = 1.f / (1.f + __expf(-gi));
      float fs = 1.f / (1.f + __expf(-gf));
      float gt = tanhf(gg);
      float os = 1.f / (1.f + __expf(-go_));
      float c  = cst[tid];
      float cn = fs * c + is * gt;
      cst[tid] = cn;
      float hn = os * tanhf(cn);
      h_last = hn;
      u16 hi = f2bf(hn), lo = f2bf(hn - bf2f(hi));
      size_t off = ((size_t)pn << 16) | ((size_t)(b0 + b) << 8) | (size_t)(cb * JP + j);
      hgHI[off] = hi; hgLO[off] = lo;
    }
    __threadfence();   // release: flush h(t+1) to device coherence point
    __syncthreads();
    if (tid == 0)
      __hip_atomic_fetch_add(cnt + bb, 1u, __ATOMIC_RELEASE, __HIP_MEMORY_SCOPE_AGENT);
  }

  // final: out[b] = sum_j h_T[j,b] * Wfc[j] + bfc
  if (tid < 16) red[tid] = 0.f;
  __syncthreads();
  {
    int j = tid >> 4, b = tid & 15;
    atomicAdd(&red[b], h_last * Wfc[cb * JP + j]);
  }
  __syncthreads();
  if (tid < 16) {
    float r = red[tid];
    if (cb == 0) r += bfc[0];
    atomicAdd(&out[b0 + tid], r);
  }
}

extern "C" void kernel_launch(void* const* d_in, const int* in_sizes, int n_in,
                              void* d_out, int out_size, void* d_ws, size_t ws_size,
                              hipStream_t stream) {
  const float* x   = (const float*)d_in[0];
  const float* Wih = (const float*)d_in[1];
  const float* Whh = (const float*)d_in[2];
  const float* bih = (const float*)d_in[3];
  const float* bhh = (const float*)d_in[4];
  const float* Wfc = (const float*)d_in[5];
  const float* bfc = (const float*)d_in[6];
  float* out = (float*)d_out;

  unsigned char* ws = (unsigned char*)d_ws;
  u32* cnt = (u32*)ws;                                  // 16 counters (256 B pad)
  u16* hHI = (u16*)(ws + 256);                          // [2][256][256] u16 = 256 KB
  u16* hLO = (u16*)(ws + 256 + 2 * 256 * 256 * sizeof(u16));
  const size_t need = 256 + 2ull * (2 * 256 * 256 * sizeof(u16));

  hipMemsetAsync(d_ws, 0, need, stream);                 // zero counters + h(0)
  hipMemsetAsync(d_out, 0, (size_t)out_size * sizeof(float), stream);
  lstm_pk<<<128, 512, 0, stream>>>(x, Wih, Whh, bih, bhh, Wfc, bfc, out, hHI, hLO, cnt);
}

// Round 2
// 3572.044 us; speedup vs baseline: 10.1522x; 10.1522x over previous
//
#include <hip/hip_runtime.h>
#include <stdint.h>
#include <math.h>

// LSTM: B=256, T=1024, I=128, H=256, O=1.
// Persistent cooperative kernel: 128 WGs x 512 threads.
//   group = 8 WGs (cb=0..7), each owns 32 h-components (all 4 gates = 128 gate rows)
//   16 batch-groups (bb=0..15) x 16 batches each.
// Weights live in VGPRs as MFMA A-fragments, split hi/lo bf16 for ~fp32 precision.
// Cross-WG h exchange: agent-scope relaxed atomics (sc1, performed at Infinity Cache).
// NO fences in the loop — sc1 store completion (vmcnt, drained by __syncthreads'
// s_waitcnt-before-s_barrier) orders data ahead of the counter increment; sc1 loads
// bypass the stale per-XCD L2. This removes the buffer_wbl2/buffer_inv per-step
// cache-maintenance that made R1 35 us/step.

typedef __attribute__((ext_vector_type(8))) __bf16 bf16x8;
typedef __attribute__((ext_vector_type(4))) float f32x4;
typedef unsigned short u16;
typedef unsigned int u32;
typedef unsigned long long u64;

#define NCB 8     // WGs per batch-group
#define BK  16    // batches per group
#define JP  32    // h-components per WG
#define TT  1024
#define HD  256
#define ID  128

__device__ __forceinline__ u16 f2bf(float f) {          // fp32 -> bf16 RNE
  u32 u = __float_as_uint(f);
  u += 0x7FFFu + ((u >> 16) & 1u);
  return (u16)(u >> 16);
}
__device__ __forceinline__ float bf2f(u16 h) { return __uint_as_float((u32)h << 16); }

__device__ __forceinline__ f32x4 mfma(bf16x8 a, bf16x8 b, f32x4 c) {
  return __builtin_amdgcn_mfma_f32_16x16x32_bf16(a, b, c, 0, 0, 0);
}

__global__ __launch_bounds__(512, 2) void lstm_pk(
    const float* __restrict__ x, const float* __restrict__ Wih,
    const float* __restrict__ Whh, const float* __restrict__ bih,
    const float* __restrict__ bhh, const float* __restrict__ Wfc,
    const float* __restrict__ bfc, float* __restrict__ out,
    u32* __restrict__ hg, u32* __restrict__ cnt)
{
  // LDS: pads chosen so b128 frag reads land 2-way bank aliased (free per m136).
  __shared__ u16 hHI[16][264], hLO[16][264];        // h stage: [batch][k], stride 528B
  __shared__ u16 xHI[2][16][136], xLO[2][16][136];  // x stage (dbuf): stride 272B
  __shared__ float gex[128 * 16];                   // gate exchange [row][batch]
  __shared__ float cst[512];                        // c state, one cell per thread
  __shared__ float bias[128];
  __shared__ u32 hstag[16][33];                     // h write regroup [b][j], pad 33
  __shared__ float red[16];

  const int tid  = threadIdx.x;
  const int bb   = blockIdx.x & 15, cb = blockIdx.x >> 4;
  const int b0   = bb * BK;
  const int lane = tid & 63, wave = tid >> 6;
  const int koff = (lane >> 4) * 8;                 // A/B frag k-offset
  const int arow = wave * 16 + (lane & 15);         // local gate-row for A frag
  const int grow = (arow >> 5) * HD + cb * JP + (arow & 31); // global W row (i,f,g,o)
  const int brow = lane & 15;                       // B frag column = batch

  // ---- weights -> VGPR fragments, hi/lo split (one-time) ----
  bf16x8 ahh_h[8], ahh_l[8], aih_h[4], aih_l[4];
#pragma unroll
  for (int kk = 0; kk < 8; ++kk) {
    const float* s = Whh + (size_t)grow * HD + kk * 32 + koff;
    float4 w0 = *(const float4*)(s), w1 = *(const float4*)(s + 4);
    float w[8] = {w0.x, w0.y, w0.z, w0.w, w1.x, w1.y, w1.z, w1.w};
    union { bf16x8 v; u16 u[8]; } th, tl;
#pragma unroll
    for (int e = 0; e < 8; ++e) {
      u16 hi = f2bf(w[e]); th.u[e] = hi; tl.u[e] = f2bf(w[e] - bf2f(hi));
    }
    ahh_h[kk] = th.v; ahh_l[kk] = tl.v;
  }
#pragma unroll
  for (int kk = 0; kk < 4; ++kk) {
    const float* s = Wih + (size_t)grow * ID + kk * 32 + koff;
    float4 w0 = *(const float4*)(s), w1 = *(const float4*)(s + 4);
    float w[8] = {w0.x, w0.y, w0.z, w0.w, w1.x, w1.y, w1.z, w1.w};
    union { bf16x8 v; u16 u[8]; } th, tl;
#pragma unroll
    for (int e = 0; e < 8; ++e) {
      u16 hi = f2bf(w[e]); th.u[e] = hi; tl.u[e] = f2bf(w[e] - bf2f(hi));
    }
    aih_h[kk] = th.v; aih_l[kk] = tl.v;
  }
  if (tid < 128) {
    int r = (tid >> 5) * HD + cb * JP + (tid & 31);
    bias[tid] = bih[r] + bhh[r];
  }
  cst[tid] = 0.f;

  auto stageX = [&](int t, int buf) {   // 16 batches x 128 elems, hi/lo bf16
    int bi = tid >> 5, e4 = (tid & 31) * 4;
    const float4 v = *(const float4*)(x + ((size_t)(b0 + bi) * TT + t) * ID + e4);
    float vf[4] = {v.x, v.y, v.z, v.w};
    u32 hw[2], lw[2];
#pragma unroll
    for (int q = 0; q < 2; ++q) {
      u16 h0 = f2bf(vf[2 * q]),           h1 = f2bf(vf[2 * q + 1]);
      u16 l0 = f2bf(vf[2 * q] - bf2f(h0)), l1 = f2bf(vf[2 * q + 1] - bf2f(h1));
      hw[q] = (u32)h0 | ((u32)h1 << 16);
      lw[q] = (u32)l0 | ((u32)l1 << 16);
    }
    *(u32*)&xHI[buf][bi][e4]     = hw[0];
    *(u32*)&xHI[buf][bi][e4 + 2] = hw[1];
    *(u32*)&xLO[buf][bi][e4]     = lw[0];
    *(u32*)&xLO[buf][bi][e4 + 2] = lw[1];
  };

  stageX(0, 0);
  __syncthreads();

  float h_last = 0.f;
  u32* mycnt = cnt + bb * 32;   // 128B-spaced counters

  for (int t = 0; t < TT; ++t) {
    const int p = t & 1, pn = p ^ 1;
    f32x4 a0 = {0, 0, 0, 0}, a1 = {0, 0, 0, 0}, a2 = {0, 0, 0, 0};

    // x-projection first: no h dependency, overlaps the spin-wait below
#pragma unroll
    for (int kk = 0; kk < 4; ++kk) {
      bf16x8 bh = *(const bf16x8*)&xHI[p][brow][kk * 32 + koff];
      bf16x8 bl = *(const bf16x8*)&xLO[p][brow][kk * 32 + koff];
      a0 = mfma(aih_h[kk], bh, a0);
      a1 = mfma(aih_h[kk], bl, a1);
      a2 = mfma(aih_l[kk], bh, a2);
    }

    // wait until all 8 group members published h(t)  (t=0: buffer pre-zeroed)
    if (t > 0 && tid == 0) {
      while (__hip_atomic_load(mycnt, __ATOMIC_RELAXED, __HIP_MEMORY_SCOPE_AGENT)
             < (u32)(NCB * t)) __builtin_amdgcn_s_sleep(2);
    }
    __syncthreads();

    { // stage h(t): 16 batches x 256 k, packed (hi|lo<<16) u32, coalesced u64 loads
      const u64* src = (const u64*)hg + (((u32)p << 15) | ((u32)b0 << 7));
#pragma unroll
      for (int e = 0; e < 4; ++e) {
        u64 v = __hip_atomic_load(src + e * 512 + tid, __ATOMIC_RELAXED,
                                  __HIP_MEMORY_SCOPE_AGENT);
        u32 w0 = (u32)v, w1 = (u32)(v >> 32);
        int bi = (e * 1024 + tid * 2) >> 8, k = (tid & 127) * 2;
        *(u32*)&hHI[bi][k] = (w0 & 0xFFFFu) | (w1 << 16);
        *(u32*)&hLO[bi][k] = (w0 >> 16) | (w1 & 0xFFFF0000u);
      }
    }
    __syncthreads();

#pragma unroll
    for (int kk = 0; kk < 8; ++kk) {
      bf16x8 bh = *(const bf16x8*)&hHI[brow][kk * 32 + koff];
      bf16x8 bl = *(const bf16x8*)&hLO[brow][kk * 32 + koff];
      a0 = mfma(ahh_h[kk], bh, a0);
      a1 = mfma(ahh_h[kk], bl, a1);
      a2 = mfma(ahh_l[kk], bh, a2);
    }

    if (t + 1 < TT) stageX(t + 1, pn);   // prefetch next x tile into other buf

    // D frag: row=(lane>>4)*4+r, col=lane&15  [m89-verified layout]
#pragma unroll
    for (int r = 0; r < 4; ++r)
      gex[(wave * 16 + (lane >> 4) * 4 + r) * 16 + (lane & 15)] = a0[r] + a1[r] + a2[r];
    __syncthreads();

    { // elementwise: one (comp j, batch b) cell per thread
      int j = tid >> 4, b = tid & 15;
      float gi  = gex[(j      ) * 16 + b] + bias[j];
      float gf  = gex[(32 + j ) * 16 + b] + bias[32 + j];
      float gg  = gex[(64 + j ) * 16 + b] + bias[64 + j];
      float go_ = gex[(96 + j ) * 16 + b] + bias[96 + j];
      float is = 1.f / (1.f + __expf(-gi));
      float fs = 1.f / (1.f + __expf(-gf));
      float gt = tanhf(gg);
      float os = 1.f / (1.f + __expf(-go_));
      float c  = cst[tid];
      float cn = fs * c + is * gt;
      cst[tid] = cn;
      float hn = os * tanhf(cn);
      h_last = hn;
      u16 hi = f2bf(hn), lo = f2bf(hn - bf2f(hi));
      hstag[b][j] = (u32)hi | ((u32)lo << 16);
    }
    __syncthreads();

    { // coalesced h publish: 32 consecutive u32 per batch row
      int b = tid >> 5, j = tid & 31;
      u32 w = hstag[b][j];
      u32 off = ((u32)pn << 16) | ((u32)(b0 + b) << 8) | (u32)(cb * JP + j);
      __hip_atomic_store(hg + off, w, __ATOMIC_RELAXED, __HIP_MEMORY_SCOPE_AGENT);
    }
    __syncthreads();   // drains each wave's vmcnt before releasing the barrier
    if (tid == 0)
      __hip_atomic_fetch_add(mycnt, 1u, __ATOMIC_RELAXED, __HIP_MEMORY_SCOPE_AGENT);
  }

  // final: out[b] = sum_j h_T[j,b] * Wfc[j] + bfc
  if (tid < 16) red[tid] = 0.f;
  __syncthreads();
  {
    int j = tid >> 4, b = tid & 15;
    atomicAdd(&red[b], h_last * Wfc[cb * JP + j]);
  }
  __syncthreads();
  if (tid < 16) {
    float r = red[tid];
    if (cb == 0) r += bfc[0];
    atomicAdd(&out[b0 + tid], r);
  }
}

extern "C" void kernel_launch(void* const* d_in, const int* in_sizes, int n_in,
                              void* d_out, int out_size, void* d_ws, size_t ws_size,
                              hipStream_t stream) {
  const float* x   = (const float*)d_in[0];
  const float* Wih = (const float*)d_in[1];
  const float* Whh = (const float*)d_in[2];
  const float* bih = (const float*)d_in[3];
  const float* bhh = (const float*)d_in[4];
  const float* Wfc = (const float*)d_in[5];
  const float* bfc = (const float*)d_in[6];
  float* out = (float*)d_out;

  unsigned char* ws = (unsigned char*)d_ws;
  u32* cnt = (u32*)ws;                         // 16 counters, 128B apart (2KB + pad)
  u32* hg  = (u32*)(ws + 4096);                // [2][256][256] packed (hi|lo) = 512KB
  const size_t need = 4096 + 2ull * 256 * 256 * sizeof(u32);

  hipMemsetAsync(d_ws, 0, need, stream);       // zero counters + h(0)
  hipMemsetAsync(d_out, 0, (size_t)out_size * sizeof(float), stream);
  lstm_pk<<<128, 512, 0, stream>>>(x, Wih, Whh, bih, bhh, Wfc, bfc, out, hg, cnt);
}

// Round 3
// 2735.641 us; speedup vs baseline: 13.2562x; 1.3057x over previous
//
#include <hip/hip_runtime.h>
#include <stdint.h>
#include <math.h>

// LSTM B=256,T=1024,I=128,H=256,O=1. Persistent kernel, 128 WGs x 512.
// Group = 8 WGs (cb), each owns 32 h-comps x all 4 gates; 16 batch-groups (bb) x 16.
// Weights in VGPRs as MFMA A-frags, hi/lo bf16 split (~fp32 precision).
// Cross-WG h exchange: TAG-IN-DATA protocol, no counters, no fences:
//   h stored as separate hi/lo bf16 arrays; comps ==0,1 (mod 4) carry a 2-bit
//   step tag (t mod 4) in their mantissa LSB (lo recomputed as residual of the
//   tweaked hi, so rel error ~2^-17). Consumers spin re-loading their slice with
//   sc0 sc1 loads until all tags match. Double-buffered by t&1; tags t vs t-2
//   differ mod 4. Overwrite of h(t) cannot begin until every WG's tag-check on
//   h(t+1) passed, which implies every WG finished reading h(t) -> no torn reads.

typedef __attribute__((ext_vector_type(8))) __bf16 bf16x8;
typedef __attribute__((ext_vector_type(4))) float f32x4;
typedef __attribute__((ext_vector_type(4))) unsigned int u32x4;
typedef unsigned short u16;
typedef unsigned int u32;
typedef unsigned long long u64;

#define BK  16
#define JP  32
#define TT  1024
#define HD  256
#define ID  128

__device__ __forceinline__ u16 f2bf(float f) {          // fp32 -> bf16 RNE
  u32 u = __float_as_uint(f);
  u += 0x7FFFu + ((u >> 16) & 1u);
  return (u16)(u >> 16);
}
__device__ __forceinline__ float bf2f(u16 h) { return __uint_as_float((u32)h << 16); }
__device__ __forceinline__ f32x4 mfma(bf16x8 a, bf16x8 b, f32x4 c) {
  return __builtin_amdgcn_mfma_f32_16x16x32_bf16(a, b, c, 0, 0, 0);
}
__device__ __forceinline__ float sigf(float x) {
  return __builtin_amdgcn_rcpf(1.f + __expf(-x));
}
__device__ __forceinline__ float tanhfast(float x) {
  float e = __expf(2.f * x);                 // x>>0: e=inf -> rcp=0 -> +1; x<<0: e=0 -> -1
  return 1.f - 2.f * __builtin_amdgcn_rcpf(e + 1.f);
}

__global__ __launch_bounds__(512, 2) void lstm_pk(
    const float* __restrict__ x, const float* __restrict__ Wih,
    const float* __restrict__ Whh, const float* __restrict__ bih,
    const float* __restrict__ bhh, const float* __restrict__ Wfc,
    const float* __restrict__ bfc, float* __restrict__ out,
    u16* __restrict__ hg)   // u16[2 parity][2 hi/lo][256 batch][256 comp] = 512KB
{
  __shared__ u16 hHi[16][264], hLo[16][264];        // h stage [batch][k], 528B rows
  __shared__ u16 xHI[2][16][136], xLO[2][16][136];  // x stage dbuf, 272B rows
  __shared__ u16 hS[2][2][16][40];                  // publish regroup [hi/lo][parity][b][j]
  __shared__ float red[8][16];

  const int tid  = threadIdx.x;
  const int bb   = blockIdx.x & 15, cb = blockIdx.x >> 4;
  const int b0   = bb * BK;
  const int lane = tid & 63, wave = tid >> 6;
  const int q    = lane >> 4, bcol = lane & 15;     // frag quarter / batch col
  const int koff = q * 8;                           // A/B frag k-offset
  const int r15  = lane & 15;
  // A-row mapping: row r -> gate (r&3), comp cb*32 + wave*4 + (r>>2).
  // Then D row 4q+r' -> gate r', comp wave*4+q: all 4 gates of one cell per lane.
  const int grow = (r15 & 3) * HD + cb * JP + wave * 4 + (r15 >> 2);
  const int jloc = wave * 4 + q;                    // this lane's comp (local 0..31)

  // ---- weights -> VGPR A-frags, hi/lo split (one-time) ----
  bf16x8 ahh_h[8], ahh_l[8], aih_h[4], aih_l[4];
#pragma unroll
  for (int kk = 0; kk < 8; ++kk) {
    const float* s = Whh + (size_t)grow * HD + kk * 32 + koff;
    float4 w0 = *(const float4*)(s), w1 = *(const float4*)(s + 4);
    float w[8] = {w0.x, w0.y, w0.z, w0.w, w1.x, w1.y, w1.z, w1.w};
    union { bf16x8 v; u16 u[8]; } th, tl;
#pragma unroll
    for (int e = 0; e < 8; ++e) {
      u16 hi = f2bf(w[e]); th.u[e] = hi; tl.u[e] = f2bf(w[e] - bf2f(hi));
    }
    ahh_h[kk] = th.v; ahh_l[kk] = tl.v;
  }
#pragma unroll
  for (int kk = 0; kk < 4; ++kk) {
    const float* s = Wih + (size_t)grow * ID + kk * 32 + koff;
    float4 w0 = *(const float4*)(s), w1 = *(const float4*)(s + 4);
    float w[8] = {w0.x, w0.y, w0.z, w0.w, w1.x, w1.y, w1.z, w1.w};
    union { bf16x8 v; u16 u[8]; } th, tl;
#pragma unroll
    for (int e = 0; e < 8; ++e) {
      u16 hi = f2bf(w[e]); th.u[e] = hi; tl.u[e] = f2bf(w[e] - bf2f(hi));
    }
    aih_h[kk] = th.v; aih_l[kk] = tl.v;
  }
  float biasr[4];
#pragma unroll
  for (int r = 0; r < 4; ++r) {
    int gr = r * HD + cb * JP + jloc;
    biasr[r] = bih[gr] + bhh[gr];
  }

  // per-thread h-slice for the tagged loader: 16B of hi + 16B of lo
  const int lb = tid >> 5;                // batch 0..15
  const int lc = (tid & 31) * 8;          // comp start (16B granule)
  const u16* pH0 = hg + (((u32)(0 * 256 + b0 + lb)) << 8) + lc;  // p=0 hi
  const u16* pL0 = hg + (((u32)(1 * 256 + b0 + lb)) << 8) + lc;  // p=0 lo
  const u16* pH1 = hg + (((u32)(2 * 256 + b0 + lb)) << 8) + lc;  // p=1 hi
  const u16* pL1 = hg + (((u32)(3 * 256 + b0 + lb)) << 8) + lc;  // p=1 lo

  { // stage x(0)
    int bi = tid >> 5, e4 = (tid & 31) * 4;
    float4 v = *(const float4*)(x + ((size_t)(b0 + bi) * TT) * ID + e4);
    float vf[4] = {v.x, v.y, v.z, v.w};
#pragma unroll
    for (int qq = 0; qq < 2; ++qq) {
      u16 h0 = f2bf(vf[2 * qq]),            h1 = f2bf(vf[2 * qq + 1]);
      u16 l0 = f2bf(vf[2 * qq] - bf2f(h0)), l1 = f2bf(vf[2 * qq + 1] - bf2f(h1));
      *(u32*)&xHI[0][bi][e4 + 2 * qq] = (u32)h0 | ((u32)h1 << 16);
      *(u32*)&xLO[0][bi][e4 + 2 * qq] = (u32)l0 | ((u32)l1 << 16);
    }
  }
  __syncthreads();

  float c_reg = 0.f, h_last = 0.f;

  for (int t = 0; t < TT; ++t) {
    const int p = t & 1, pn = p ^ 1;
    const u32 tag  = (u32)t & 3u;
    const u32 pat  = (tag & 1u) | ((tag >> 1) << 16);
    const u32 tagn = (u32)(t + 1) & 3u;
    const u16* aH = p ? pH1 : pH0;
    const u16* aL = p ? pL1 : pL0;

    // issue tagged h(t) slice loads (sc0 sc1: coherent, bypass stale caches)
    u32x4 f0, f1;
    asm volatile("global_load_dwordx4 %0, %2, off sc0 sc1\n\t"
                 "global_load_dwordx4 %1, %3, off sc0 sc1"
                 : "=v"(f0), "=v"(f1) : "v"(aH), "v"(aL));

    // x-projection MFMAs overlap the h flight
    f32x4 a0 = {0, 0, 0, 0}, a1 = {0, 0, 0, 0}, a2 = {0, 0, 0, 0};
#pragma unroll
    for (int kk = 0; kk < 4; ++kk) {
      bf16x8 bh = *(const bf16x8*)&xHI[p][bcol][kk * 32 + koff];
      bf16x8 bl = *(const bf16x8*)&xLO[p][bcol][kk * 32 + koff];
      a0 = mfma(aih_h[kk], bh, a0);
      a1 = mfma(aih_h[kk], bl, a1);
      a2 = mfma(aih_l[kk], bh, a2);
    }

    // tag-check retry: every 8B granule carries 2 tag bits (bit0: comp%4==0 hi-LSB
    // -> bit0 of word0; bit1: comp%4==1 -> bit16 of word0). Words 0,2 of each x4.
    for (;;) {
      asm volatile("s_waitcnt vmcnt(0)" : "+v"(f0), "+v"(f1));
      u32 ok = (u32)((f0[0] & 0x10001u) == pat) & (u32)((f0[2] & 0x10001u) == pat)
             & (u32)((f1[0] & 0x10001u) == pat) & (u32)((f1[2] & 0x10001u) == pat);
      if (__all((int)ok)) break;
      __builtin_amdgcn_s_sleep(1);
      asm volatile("global_load_dwordx4 %0, %2, off sc0 sc1\n\t"
                   "global_load_dwordx4 %1, %3, off sc0 sc1\n\t"
                   "s_waitcnt vmcnt(0)"
                   : "=v"(f0), "=v"(f1) : "v"(aH), "v"(aL) : "memory");
    }

    // x(t+1) -> regs (latency hidden under barrier+MFMA+elementwise)
    float4 xv;
    if (t + 1 < TT)
      xv = *(const float4*)(x + ((size_t)(b0 + (tid >> 5)) * TT + (t + 1)) * ID + (tid & 31) * 4);

    *(u32x4*)&hHi[lb][lc] = f0;
    *(u32x4*)&hLo[lb][lc] = f1;
    __syncthreads();                                   // barrier A: h(t) staged

#pragma unroll
    for (int kk = 0; kk < 8; ++kk) {
      bf16x8 bh = *(const bf16x8*)&hHi[bcol][kk * 32 + koff];
      bf16x8 bl = *(const bf16x8*)&hLo[bcol][kk * 32 + koff];
      a0 = mfma(ahh_h[kk], bh, a0);
      a1 = mfma(ahh_h[kk], bl, a1);
      a2 = mfma(ahh_l[kk], bh, a2);
    }

    { // in-lane elementwise: this lane owns all 4 gates of (jloc, bcol)
      float g0 = a0[0] + a1[0] + a2[0] + biasr[0];
      float g1 = a0[1] + a1[1] + a2[1] + biasr[1];
      float g2 = a0[2] + a1[2] + a2[2] + biasr[2];
      float g3 = a0[3] + a1[3] + a2[3] + biasr[3];
      float ig = sigf(g0), fg = sigf(g1), gg = tanhfast(g2), og = sigf(g3);
      c_reg = fg * c_reg + ig * gg;
      float hn = og * tanhfast(c_reg);
      h_last = hn;
      u32 hi = f2bf(hn);
      if (q == 0) hi = (hi & ~1u) | (tagn & 1u);
      if (q == 1) hi = (hi & ~1u) | ((tagn >> 1) & 1u);
      u16 hi16 = (u16)hi;
      u32 lo = f2bf(hn - bf2f(hi16));
      if (q == 0) lo = (lo & ~1u) | (tagn & 1u);
      if (q == 1) lo = (lo & ~1u) | ((tagn >> 1) & 1u);
      hS[0][p][bcol][jloc] = hi16;
      hS[1][p][bcol][jloc] = (u16)lo;
    }

    if (t + 1 < TT) { // stage x(t+1) -> xHI/xLO[pn]
      float vf[4] = {xv.x, xv.y, xv.z, xv.w};
      int bi = tid >> 5, e4 = (tid & 31) * 4;
#pragma unroll
      for (int qq = 0; qq < 2; ++qq) {
        u16 h0 = f2bf(vf[2 * qq]),            h1 = f2bf(vf[2 * qq + 1]);
        u16 l0 = f2bf(vf[2 * qq] - bf2f(h0)), l1 = f2bf(vf[2 * qq + 1] - bf2f(h1));
        *(u32*)&xHI[pn][bi][e4 + 2 * qq] = (u32)h0 | ((u32)h1 << 16);
        *(u32*)&xLO[pn][bi][e4 + 2 * qq] = (u32)l0 | ((u32)l1 << 16);
      }
    }
    __syncthreads();                                   // barrier B: hS + x ready

    if (tid >= 256) { // publish h(t+1): 256 threads, coalesced u64, fire-and-forget
      int t2 = tid - 256, a = t2 >> 7, rem = t2 & 127, b = rem >> 3, ch = rem & 7;
      u64 v = *(const u64*)&hS[a][p][b][ch * 4];
      const u16* dst = hg + (((u32)((pn * 2 + a) * 256 + b0 + b)) << 8)
                          + (u32)(cb * JP + ch * 4);
      asm volatile("global_store_dwordx2 %0, %1, off sc0 sc1"
                   :: "v"(dst), "v"(v) : "memory");
    }
  }

  // epilogue: out[b] = sum_j h_T[j,b] * Wfc[j] (+ bfc once)
  {
    float v = h_last * Wfc[cb * JP + jloc];
    v += __shfl_xor(v, 16);
    v += __shfl_xor(v, 32);
    if (lane < 16) red[wave][lane] = v;
  }
  __syncthreads();
  if (tid < 16) {
    float s = 0.f;
#pragma unroll
    for (int w = 0; w < 8; ++w) s += red[w][tid];
    if (cb == 0) s += bfc[0];
    atomicAdd(&out[b0 + tid], s);
  }
}

extern "C" void kernel_launch(void* const* d_in, const int* in_sizes, int n_in,
                              void* d_out, int out_size, void* d_ws, size_t ws_size,
                              hipStream_t stream) {
  const float* x   = (const float*)d_in[0];
  const float* Wih = (const float*)d_in[1];
  const float* Whh = (const float*)d_in[2];
  const float* bih = (const float*)d_in[3];
  const float* bhh = (const float*)d_in[4];
  const float* Wfc = (const float*)d_in[5];
  const float* bfc = (const float*)d_in[6];
  float* out = (float*)d_out;

  u16* hg = (u16*)d_ws;                            // [2][2][256][256] u16 = 512KB
  const size_t need = 4ull * 256 * 256 * sizeof(u16);

  hipMemsetAsync(d_ws, 0, need, stream);           // h(0)=0 with tag bits = 0
  hipMemsetAsync(d_out, 0, (size_t)out_size * sizeof(float), stream);
  lstm_pk<<<128, 512, 0, stream>>>(x, Wih, Whh, bih, bhh, Wfc, bfc, out, hg);
}